// Round 2
// baseline (551.344 us; speedup 1.0000x reference)
//
#include <hip/hip_runtime.h>
#include <cstdint>

#define BATCH 2
#define CCH 128
#define H2 64
#define NP 4096      /* 64*64 patches */
#define H1 128
#define YPB (CCH*H1*H1) /* 2097152 per batch */

// ---------------- K1: mask patch all-zero test + ordered compaction ----------
__global__ void k1_compact(const float* __restrict__ mask, int* __restrict__ cnt,
                           int* __restrict__ idx)
{
    int b = blockIdx.x;
    int lane = threadIdx.x;
    const float* mb = mask + b * (H2*H2);
    int count = 0;
    for (int it = 0; it < 64; ++it) {
        int p = it * 64 + lane;
        int ph = p >> 6, pw = p & 63;
        float s = 0.f;
        #pragma unroll
        for (int dh = -1; dh <= 1; ++dh) {
            int r = ph + dh;
            if ((unsigned)r < (unsigned)H2) {
                #pragma unroll
                for (int dw = -1; dw <= 1; ++dw) {
                    int c = pw + dw;
                    if ((unsigned)c < (unsigned)H2) s += mb[r*H2 + c];
                }
            }
        }
        bool flag = (s == 0.0f);
        unsigned long long m = __ballot(flag);
        int pre = __popcll(m & ((1ull << lane) - 1ull));
        if (flag) idx[b*NP + count + pre] = p;
        count += __popcll(m);
    }
    if (lane == 0) cnt[b] = count;
}

// ---------------- K2: 1/max(||patch_q||, 1e-4) for selected q ----------------
__global__ void k2_norms(const float* __restrict__ x2, const int* __restrict__ cnt,
                         const int* __restrict__ idx, float* __restrict__ rnorm)
{
    int cnt0 = cnt[0], cnt1 = cnt[1];
    int total = cnt0 + cnt1;
    int lane = threadIdx.x;
    for (int item = blockIdx.x; item < total; item += gridDim.x) {
        int b, j;
        if (item < cnt0) { b = 0; j = item; } else { b = 1; j = item - cnt0; }
        int p = idx[b*NP + j];
        int qh = p >> 6, qw = p & 63;
        const float* xb = x2 + (size_t)b * CCH * H2 * H2;
        float s = 0.f;
        for (int c = lane; c < CCH; c += 64) {
            const float* xc = xb + (size_t)c * H2 * H2;
            #pragma unroll
            for (int dh = -1; dh <= 1; ++dh) {
                int r = qh + dh;
                if ((unsigned)r < (unsigned)H2) {
                    #pragma unroll
                    for (int dw = -1; dw <= 1; ++dw) {
                        int cc = qw + dw;
                        if ((unsigned)cc < (unsigned)H2) { float v = xc[r*H2 + cc]; s += v*v; }
                    }
                }
            }
        }
        #pragma unroll
        for (int off = 32; off > 0; off >>= 1) s += __shfl_down(s, off, 64);
        if (lane == 0) rnorm[b*NP + j] = 1.0f / fmaxf(sqrtf(s), 1e-4f);
    }
}

// ---------------- init online-softmax stats: M=0, D = #masked ----------------
__global__ void k_init_stats(float* __restrict__ M, float* __restrict__ D,
                             const int* __restrict__ cnt)
{
    int t = blockIdx.x * blockDim.x + threadIdx.x;
    if (t >= BATCH*NP) return;
    int b = t >> 12;
    M[t] = 0.f;
    D[t] = (float)(NP - cnt[b]);
}

// ---------------- K3: S[q,s] = <patch_s, patch_q> * rnorm_q -----------------
__global__ void k3_scores(const float* __restrict__ x2, const int* __restrict__ cnt,
                          const int* __restrict__ idx, const float* __restrict__ rnorm,
                          float* __restrict__ S, int base, int CQ)
{
    __shared__ float f[9*CCH];
    int lane = threadIdx.x;
    int cnt0 = cnt[0], cnt1 = cnt[1];
    int nb0 = min(max(cnt0 - base, 0), CQ);
    int nb1 = min(max(cnt1 - base, 0), CQ);
    long total = (long)(nb0 + nb1) * 64;
    for (long item = blockIdx.x; item < total; item += gridDim.x) {
        int b, rem;
        if (item < (long)nb0*64) { b = 0; rem = (int)item; }
        else                     { b = 1; rem = (int)(item - (long)nb0*64); }
        int jq = rem >> 6;
        int h  = rem & 63;
        int jg = base + jq;
        int p = idx[b*NP + jg];
        int qh = p >> 6, qw = p & 63;
        float rn = rnorm[b*NP + jg];
        const float* xb = x2 + (size_t)b * CCH * H2 * H2;
        // stage normalized filter [9][128] in LDS
        for (int t2 = lane; t2 < 9*CCH; t2 += 64) {
            int k = t2 >> 7, c = t2 & 127;
            int dh = k / 3, dw = k % 3;
            int r = qh + dh - 1, cc = qw + dw - 1;
            float v = 0.f;
            if ((unsigned)r < (unsigned)H2 && (unsigned)cc < (unsigned)H2)
                v = xb[((size_t)c*H2 + r)*H2 + cc];
            f[t2] = v * rn;
        }
        __syncthreads();
        float a0=0.f,a1=0.f,a2=0.f,a3=0.f;
        #pragma unroll
        for (int k = 0; k < 9; ++k) {
            int dh = k/3, dw = k%3;
            int rr = h + dh - 1;
            int cc = lane + dw - 1;
            if ((unsigned)rr < (unsigned)H2 && (unsigned)cc < (unsigned)H2) {
                const float* xp = xb + (size_t)rr*H2 + cc;
                const float* fp = f + k*CCH;
                for (int c = 0; c < CCH; c += 4) {
                    a0 += xp[(size_t)(c+0)*H2*H2] * fp[c+0];
                    a1 += xp[(size_t)(c+1)*H2*H2] * fp[c+1];
                    a2 += xp[(size_t)(c+2)*H2*H2] * fp[c+2];
                    a3 += xp[(size_t)(c+3)*H2*H2] * fp[c+3];
                }
            }
        }
        float sv = (a0+a1)+(a2+a3);
        S[((size_t)(b*CQ + jq))*NP + h*64 + lane] = sv;
        __syncthreads();  // protect f before next item's reload
    }
}

// ---------------- K3b: online softmax stats over this chunk ------------------
__global__ void k3b_stats(const float* __restrict__ S, const int* __restrict__ cnt,
                          float* __restrict__ M, float* __restrict__ D, int base, int CQ)
{
    int t = blockIdx.x*blockDim.x + threadIdx.x;
    if (t >= BATCH*NP) return;
    int b = t >> 12, s = t & (NP-1);
    int n = min(max(cnt[b] - base, 0), CQ);
    if (n == 0) return;
    float m = M[t], d = D[t];
    for (int j = 0; j < n; ++j) {
        float l = 10.f * S[((size_t)(b*CQ + j))*NP + s];
        if (l > m) { d = d*__expf(m - l) + 1.f; m = l; }
        else       { d += __expf(l - m); }
    }
    M[t] = m; D[t] = d;
}

// ---------------- K4b: A = exp(10 S - M) / D (in place) ----------------------
__global__ void k4b_normalize(float* __restrict__ S, const int* __restrict__ cnt,
                              const float* __restrict__ M, const float* __restrict__ D,
                              int base, int CQ)
{
    int cnt0 = cnt[0], cnt1 = cnt[1];
    int nb0 = min(max(cnt0 - base, 0), CQ);
    int nb1 = min(max(cnt1 - base, 0), CQ);
    int total = nb0 + nb1;
    for (int item = blockIdx.x; item < total; item += gridDim.x) {
        int b, jq;
        if (item < nb0) { b = 0; jq = item; } else { b = 1; jq = item - nb0; }
        float* row = S + ((size_t)(b*CQ + jq))*NP;
        const float* Mb = M + b*NP;
        const float* Db = D + b*NP;
        for (int s = threadIdx.x; s < NP; s += blockDim.x)
            row[s] = __expf(10.f*row[s] - Mb[s]) / Db[s];
    }
}

// ---------------- K5: gather-form transposed conv (paste patches) ------------
__global__ void k5_paste(const float* __restrict__ A, const int* __restrict__ cnt,
                         const int* __restrict__ idx, const float* __restrict__ x1,
                         float* __restrict__ y, int base, int CQ, int accumulate)
{
    int t = blockIdx.x*blockDim.x + threadIdx.x;
    if (t >= BATCH*YPB) return;
    int ow = t & 127;
    int oh = (t >> 7) & 127;
    int co = (t >> 14) & 127;
    int b  = t >> 21;
    int n = min(max(cnt[b] - base, 0), CQ);
    if (n == 0) { if (!accumulate) y[t] = 0.f; return; }
    int aA[2], ihA[2], na = 0;
    #pragma unroll
    for (int a = 0; a < 4; ++a) {
        int ih2 = oh + 1 - a;
        if ((ih2 & 1) == 0 && ih2 >= 0 && ih2 < 2*H2) { aA[na] = a; ihA[na] = ih2 >> 1; ++na; }
    }
    int bA[2], iwA[2], nbv = 0;
    #pragma unroll
    for (int a = 0; a < 4; ++a) {
        int iw2 = ow + 1 - a;
        if ((iw2 & 1) == 0 && iw2 >= 0 && iw2 < 2*H2) { bA[nbv] = a; iwA[nbv] = iw2 >> 1; ++nbv; }
    }
    const float* x1b = x1 + ((size_t)(b*CCH + co))*H1*H1;
    const int* idxb = idx + b*NP + base;
    float acc = 0.f;
    for (int j = 0; j < n; ++j) {
        int p = idxb[j];
        int qh = p >> 6, qw = p & 63;
        const float* Arow = A + ((size_t)(b*CQ + j))*NP;
        for (int ia = 0; ia < na; ++ia) {
            int rr = 2*qh + aA[ia] - 1;
            if ((unsigned)rr >= (unsigned)H1) continue;
            for (int ib = 0; ib < nbv; ++ib) {
                int cc = 2*qw + bA[ib] - 1;
                float xv = ((unsigned)cc < (unsigned)H1) ? x1b[rr*H1 + cc] : 0.f;
                acc += Arow[(ihA[ia] << 6) + iwA[ib]] * xv;
            }
        }
    }
    acc *= 0.25f;
    y[t] = accumulate ? (y[t] + acc) : acc;
}

// ---------------- K6: 4 dilated 3x3 convs + bias + relu, fused ---------------
// v2: 512-thread blocks; each 128-lane group reduces a 32-channel chunk,
// LDS cross-group reduce. Grid unchanged (1024 blocks) but 8 waves/block
// -> 32 waves/CU occupancy (was 8).
__global__ void __launch_bounds__(512) k6_final(const float* __restrict__ y,
    const float* __restrict__ fw0, const float* __restrict__ fb0,
    const float* __restrict__ fw1, const float* __restrict__ fb1,
    const float* __restrict__ fw2, const float* __restrict__ fb2,
    const float* __restrict__ fw3, const float* __restrict__ fb3,
    float* __restrict__ out)
{
    __shared__ float red[3][16][H1];   // 24 KB
    int t  = threadIdx.x;
    int ow = t & 127;
    int wg = t >> 7;                   // 0..3 channel chunk
    int oh = blockIdx.x;
    int g  = blockIdx.y;
    int b  = blockIdx.z;
    const float* fw = (g==0)?fw0:(g==1)?fw1:(g==2)?fw2:fw3;
    const float* fb = (g==0)?fb0:(g==1)?fb1:(g==2)?fb2:fb3;
    int r = 1 << g;
    float acc[16];
    #pragma unroll
    for (int o = 0; o < 16; ++o) acc[o] = 0.f;
    const float* yb = y + (size_t)b*YPB;
    int c0 = wg * 32;
    for (int c = c0; c < c0 + 32; ++c) {
        const float* yc = yb + (size_t)c*H1*H1;
        float v[9];
        #pragma unroll
        for (int dh = 0; dh < 3; ++dh) {
            int rr = oh + r*(dh-1);
            bool rok = (unsigned)rr < (unsigned)H1;
            #pragma unroll
            for (int dw = 0; dw < 3; ++dw) {
                int cc = ow + r*(dw-1);
                v[dh*3+dw] = (rok && (unsigned)cc < (unsigned)H1) ? yc[rr*H1 + cc] : 0.f;
            }
        }
        #pragma unroll
        for (int o = 0; o < 16; ++o) {
            const float* w = fw + ((size_t)o*CCH + c)*9;   // uniform -> s_load
            #pragma unroll
            for (int k = 0; k < 9; ++k) acc[o] += v[k]*w[k];
        }
    }
    if (wg > 0) {
        #pragma unroll
        for (int o = 0; o < 16; ++o) red[wg-1][o][ow] = acc[o];
    }
    __syncthreads();
    if (wg == 0) {
        size_t obase = ((size_t)(b*64 + g*16)*H1 + oh)*H1 + ow;
        #pragma unroll
        for (int o = 0; o < 16; ++o) {
            float s = acc[o] + red[0][o][ow] + red[1][o][ow] + red[2][o][ow] + fb[o];
            out[obase + (size_t)o*H1*H1] = fmaxf(s, 0.f);
        }
    }
}

extern "C" void kernel_launch(void* const* d_in, const int* in_sizes, int n_in,
                              void* d_out, int out_size, void* d_ws, size_t ws_size,
                              hipStream_t stream)
{
    const float* x1   = (const float*)d_in[0];
    const float* x2   = (const float*)d_in[1];
    const float* mask = (const float*)d_in[2];
    const float* fw0 = (const float*)d_in[3];
    const float* fb0 = (const float*)d_in[4];
    const float* fw1 = (const float*)d_in[5];
    const float* fb1 = (const float*)d_in[6];
    const float* fw2 = (const float*)d_in[7];
    const float* fb2 = (const float*)d_in[8];
    const float* fw3 = (const float*)d_in[9];
    const float* fb3 = (const float*)d_in[10];
    float* out = (float*)d_out;
    char* ws = (char*)d_ws;

    size_t off = 0;
    auto alloc = [&](size_t bytes) { size_t o = off; off += (bytes + 255) & ~(size_t)255; return o; };
    size_t cnt_off = alloc(BATCH*sizeof(int));
    size_t idx_off = alloc((size_t)BATCH*NP*sizeof(int));
    size_t rn_off  = alloc((size_t)BATCH*NP*sizeof(float));
    size_t M_off   = alloc((size_t)BATCH*NP*sizeof(float));
    size_t D_off   = alloc((size_t)BATCH*NP*sizeof(float));
    size_t y_off   = alloc((size_t)BATCH*YPB*sizeof(float));
    size_t remain = (ws_size > off) ? (ws_size - off) : 0;
    int CQ = (int)(remain / ((size_t)BATCH*NP*sizeof(float)));
    if (CQ > NP) CQ = NP;
    if (CQ < 1) CQ = 1;
    size_t S_off = off;
    int NCH = (NP + CQ - 1) / CQ;

    int* cnt   = (int*)(ws + cnt_off);
    int* idx   = (int*)(ws + idx_off);
    float* rnm = (float*)(ws + rn_off);
    float* Mv  = (float*)(ws + M_off);
    float* Dv  = (float*)(ws + D_off);
    float* y   = (float*)(ws + y_off);
    float* S   = (float*)(ws + S_off);

    k1_compact<<<BATCH, 64, 0, stream>>>(mask, cnt, idx);
    k2_norms<<<256, 64, 0, stream>>>(x2, cnt, idx, rnm);
    k_init_stats<<<(BATCH*NP+255)/256, 256, 0, stream>>>(Mv, Dv, cnt);
    for (int ch = 0; ch < NCH; ++ch) {
        k3_scores<<<2048, 64, 0, stream>>>(x2, cnt, idx, rnm, S, ch*CQ, CQ);
        k3b_stats<<<(BATCH*NP+255)/256, 256, 0, stream>>>(S, cnt, Mv, Dv, ch*CQ, CQ);
    }
    for (int ch = 0; ch < NCH; ++ch) {
        if (NCH > 1)
            k3_scores<<<2048, 64, 0, stream>>>(x2, cnt, idx, rnm, S, ch*CQ, CQ);
        k4b_normalize<<<256, 256, 0, stream>>>(S, cnt, Mv, Dv, ch*CQ, CQ);
        k5_paste<<<(BATCH*YPB+255)/256, 256, 0, stream>>>(S, cnt, idx, x1, y, ch*CQ, CQ, ch > 0 ? 1 : 0);
    }
    k6_final<<<dim3(H1, 4, BATCH), 512, 0, stream>>>(y, fw0, fb0, fw1, fb1, fw2, fb2, fw3, fb3, out);
}

// Round 3
// 407.353 us; speedup vs baseline: 1.3535x; 1.3535x over previous
//
#include <hip/hip_runtime.h>
#include <cstdint>

#define BATCH 2
#define CCH 128
#define H2 64
#define NP 4096      /* 64*64 patches */
#define H1 128
#define YPB (CCH*H1*H1) /* 2097152 per batch */

// ---------------- K1: mask patch all-zero test + ordered compaction ----------
__global__ void k1_compact(const float* __restrict__ mask, int* __restrict__ cnt,
                           int* __restrict__ idx)
{
    int b = blockIdx.x;
    int lane = threadIdx.x;
    const float* mb = mask + b * (H2*H2);
    int count = 0;
    for (int it = 0; it < 64; ++it) {
        int p = it * 64 + lane;
        int ph = p >> 6, pw = p & 63;
        float s = 0.f;
        #pragma unroll
        for (int dh = -1; dh <= 1; ++dh) {
            int r = ph + dh;
            if ((unsigned)r < (unsigned)H2) {
                #pragma unroll
                for (int dw = -1; dw <= 1; ++dw) {
                    int c = pw + dw;
                    if ((unsigned)c < (unsigned)H2) s += mb[r*H2 + c];
                }
            }
        }
        bool flag = (s == 0.0f);
        unsigned long long m = __ballot(flag);
        int pre = __popcll(m & ((1ull << lane) - 1ull));
        if (flag) idx[b*NP + count + pre] = p;
        count += __popcll(m);
    }
    if (lane == 0) cnt[b] = count;
}

// ---------------- K2: 1/max(||patch_q||, 1e-4) for selected q ----------------
__global__ void k2_norms(const float* __restrict__ x2, const int* __restrict__ cnt,
                         const int* __restrict__ idx, float* __restrict__ rnorm)
{
    int cnt0 = cnt[0], cnt1 = cnt[1];
    int total = cnt0 + cnt1;
    int lane = threadIdx.x;
    for (int item = blockIdx.x; item < total; item += gridDim.x) {
        int b, j;
        if (item < cnt0) { b = 0; j = item; } else { b = 1; j = item - cnt0; }
        int p = idx[b*NP + j];
        int qh = p >> 6, qw = p & 63;
        const float* xb = x2 + (size_t)b * CCH * H2 * H2;
        float s = 0.f;
        for (int c = lane; c < CCH; c += 64) {
            const float* xc = xb + (size_t)c * H2 * H2;
            #pragma unroll
            for (int dh = -1; dh <= 1; ++dh) {
                int r = qh + dh;
                if ((unsigned)r < (unsigned)H2) {
                    #pragma unroll
                    for (int dw = -1; dw <= 1; ++dw) {
                        int cc = qw + dw;
                        if ((unsigned)cc < (unsigned)H2) { float v = xc[r*H2 + cc]; s += v*v; }
                    }
                }
            }
        }
        #pragma unroll
        for (int off = 32; off > 0; off >>= 1) s += __shfl_down(s, off, 64);
        if (lane == 0) rnorm[b*NP + j] = 1.0f / fmaxf(sqrtf(s), 1e-4f);
    }
}

// ---------------- init online-softmax stats: M=0, D = #masked ----------------
__global__ void k_init_stats(float* __restrict__ M, float* __restrict__ D,
                             const int* __restrict__ cnt)
{
    int t = blockIdx.x * blockDim.x + threadIdx.x;
    if (t >= BATCH*NP) return;
    int b = t >> 12;
    M[t] = 0.f;
    D[t] = (float)(NP - cnt[b]);
}

// ---------------- K3: S[q,s] = <patch_s, patch_q> * rnorm_q -----------------
__global__ void k3_scores(const float* __restrict__ x2, const int* __restrict__ cnt,
                          const int* __restrict__ idx, const float* __restrict__ rnorm,
                          float* __restrict__ S, int base, int CQ)
{
    __shared__ float f[9*CCH];
    int lane = threadIdx.x;
    int cnt0 = cnt[0], cnt1 = cnt[1];
    int nb0 = min(max(cnt0 - base, 0), CQ);
    int nb1 = min(max(cnt1 - base, 0), CQ);
    long total = (long)(nb0 + nb1) * 64;
    for (long item = blockIdx.x; item < total; item += gridDim.x) {
        int b, rem;
        if (item < (long)nb0*64) { b = 0; rem = (int)item; }
        else                     { b = 1; rem = (int)(item - (long)nb0*64); }
        int jq = rem >> 6;
        int h  = rem & 63;
        int jg = base + jq;
        int p = idx[b*NP + jg];
        int qh = p >> 6, qw = p & 63;
        float rn = rnorm[b*NP + jg];
        const float* xb = x2 + (size_t)b * CCH * H2 * H2;
        // stage normalized filter [9][128] in LDS
        for (int t2 = lane; t2 < 9*CCH; t2 += 64) {
            int k = t2 >> 7, c = t2 & 127;
            int dh = k / 3, dw = k % 3;
            int r = qh + dh - 1, cc = qw + dw - 1;
            float v = 0.f;
            if ((unsigned)r < (unsigned)H2 && (unsigned)cc < (unsigned)H2)
                v = xb[((size_t)c*H2 + r)*H2 + cc];
            f[t2] = v * rn;
        }
        __syncthreads();
        float a0=0.f,a1=0.f,a2=0.f,a3=0.f;
        #pragma unroll
        for (int k = 0; k < 9; ++k) {
            int dh = k/3, dw = k%3;
            int rr = h + dh - 1;
            int cc = lane + dw - 1;
            if ((unsigned)rr < (unsigned)H2 && (unsigned)cc < (unsigned)H2) {
                const float* xp = xb + (size_t)rr*H2 + cc;
                const float* fp = f + k*CCH;
                for (int c = 0; c < CCH; c += 4) {
                    a0 += xp[(size_t)(c+0)*H2*H2] * fp[c+0];
                    a1 += xp[(size_t)(c+1)*H2*H2] * fp[c+1];
                    a2 += xp[(size_t)(c+2)*H2*H2] * fp[c+2];
                    a3 += xp[(size_t)(c+3)*H2*H2] * fp[c+3];
                }
            }
        }
        float sv = (a0+a1)+(a2+a3);
        S[((size_t)(b*CQ + jq))*NP + h*64 + lane] = sv;
        __syncthreads();  // protect f before next item's reload
    }
}

// ---------------- K3b: online softmax stats over this chunk ------------------
__global__ void k3b_stats(const float* __restrict__ S, const int* __restrict__ cnt,
                          float* __restrict__ M, float* __restrict__ D, int base, int CQ)
{
    int t = blockIdx.x*blockDim.x + threadIdx.x;
    if (t >= BATCH*NP) return;
    int b = t >> 12, s = t & (NP-1);
    int n = min(max(cnt[b] - base, 0), CQ);
    if (n == 0) return;
    float m = M[t], d = D[t];
    for (int j = 0; j < n; ++j) {
        float l = 10.f * S[((size_t)(b*CQ + j))*NP + s];
        if (l > m) { d = d*__expf(m - l) + 1.f; m = l; }
        else       { d += __expf(l - m); }
    }
    M[t] = m; D[t] = d;
}

// ---------------- K4b: A = exp(10 S - M) / D (in place) ----------------------
__global__ void k4b_normalize(float* __restrict__ S, const int* __restrict__ cnt,
                              const float* __restrict__ M, const float* __restrict__ D,
                              int base, int CQ)
{
    int cnt0 = cnt[0], cnt1 = cnt[1];
    int nb0 = min(max(cnt0 - base, 0), CQ);
    int nb1 = min(max(cnt1 - base, 0), CQ);
    int total = nb0 + nb1;
    for (int item = blockIdx.x; item < total; item += gridDim.x) {
        int b, jq;
        if (item < nb0) { b = 0; jq = item; } else { b = 1; jq = item - nb0; }
        float* row = S + ((size_t)(b*CQ + jq))*NP;
        const float* Mb = M + b*NP;
        const float* Db = D + b*NP;
        for (int s = threadIdx.x; s < NP; s += blockDim.x)
            row[s] = __expf(10.f*row[s] - Mb[s]) / Db[s];
    }
}

// ---------------- K5: gather-form transposed conv (paste patches) ------------
__global__ void k5_paste(const float* __restrict__ A, const int* __restrict__ cnt,
                         const int* __restrict__ idx, const float* __restrict__ x1,
                         float* __restrict__ y, int base, int CQ, int accumulate)
{
    int t = blockIdx.x*blockDim.x + threadIdx.x;
    if (t >= BATCH*YPB) return;
    int ow = t & 127;
    int oh = (t >> 7) & 127;
    int co = (t >> 14) & 127;
    int b  = t >> 21;
    int n = min(max(cnt[b] - base, 0), CQ);
    if (n == 0) { if (!accumulate) y[t] = 0.f; return; }
    int aA[2], ihA[2], na = 0;
    #pragma unroll
    for (int a = 0; a < 4; ++a) {
        int ih2 = oh + 1 - a;
        if ((ih2 & 1) == 0 && ih2 >= 0 && ih2 < 2*H2) { aA[na] = a; ihA[na] = ih2 >> 1; ++na; }
    }
    int bA[2], iwA[2], nbv = 0;
    #pragma unroll
    for (int a = 0; a < 4; ++a) {
        int iw2 = ow + 1 - a;
        if ((iw2 & 1) == 0 && iw2 >= 0 && iw2 < 2*H2) { bA[nbv] = a; iwA[nbv] = iw2 >> 1; ++nbv; }
    }
    const float* x1b = x1 + ((size_t)(b*CCH + co))*H1*H1;
    const int* idxb = idx + b*NP + base;
    float acc = 0.f;
    for (int j = 0; j < n; ++j) {
        int p = idxb[j];
        int qh = p >> 6, qw = p & 63;
        const float* Arow = A + ((size_t)(b*CQ + j))*NP;
        for (int ia = 0; ia < na; ++ia) {
            int rr = 2*qh + aA[ia] - 1;
            if ((unsigned)rr >= (unsigned)H1) continue;
            for (int ib = 0; ib < nbv; ++ib) {
                int cc = 2*qw + bA[ib] - 1;
                float xv = ((unsigned)cc < (unsigned)H1) ? x1b[rr*H1 + cc] : 0.f;
                acc += Arow[(ihA[ia] << 6) + iwA[ib]] * xv;
            }
        }
    }
    acc *= 0.25f;
    y[t] = accumulate ? (y[t] + acc) : acc;
}

// ---------------- K6: 4 dilated 3x3 convs + bias + relu, fused ---------------
// v3: 512-thread blocks; each 128-lane group computes 4 of the 16 output
// channels over ALL input channels. og via readfirstlane -> SGPR -> weight
// and bias addresses provably wave-uniform -> s_load (v2's regression was
// divergent weight loads: tid>>7 is wave-uniform but LLVM divergence
// analysis can't prove it). 1024 blocks x 8 waves = 32 waves/CU.
__global__ void __launch_bounds__(512) k6_final(const float* __restrict__ y,
    const float* __restrict__ fw0, const float* __restrict__ fb0,
    const float* __restrict__ fw1, const float* __restrict__ fb1,
    const float* __restrict__ fw2, const float* __restrict__ fb2,
    const float* __restrict__ fw3, const float* __restrict__ fb3,
    float* __restrict__ out)
{
    int t  = threadIdx.x;
    int ow = t & 127;
    int og = __builtin_amdgcn_readfirstlane(t >> 7);   // 0..3, wave-uniform SGPR
    int oh = blockIdx.x;
    int g  = blockIdx.y;
    int b  = blockIdx.z;
    const float* fw = (g==0)?fw0:(g==1)?fw1:(g==2)?fw2:fw3;
    const float* fb = (g==0)?fb0:(g==1)?fb1:(g==2)?fb2:fb3;
    int r = 1 << g;
    float acc[4];
    #pragma unroll
    for (int o = 0; o < 4; ++o) acc[o] = 0.f;
    const float* yb = y + (size_t)b*YPB;
    const float* fwg = fw + (size_t)og*4*CCH*9;        // uniform base
    for (int c = 0; c < CCH; ++c) {
        const float* yc = yb + (size_t)c*H1*H1;
        float v[9];
        #pragma unroll
        for (int dh = 0; dh < 3; ++dh) {
            int rr = oh + r*(dh-1);
            bool rok = (unsigned)rr < (unsigned)H1;
            #pragma unroll
            for (int dw = 0; dw < 3; ++dw) {
                int cc = ow + r*(dw-1);
                v[dh*3+dw] = (rok && (unsigned)cc < (unsigned)H1) ? yc[rr*H1 + cc] : 0.f;
            }
        }
        #pragma unroll
        for (int o = 0; o < 4; ++o) {
            const float* w = fwg + ((size_t)o*CCH + c)*9;   // uniform -> s_load
            #pragma unroll
            for (int k = 0; k < 9; ++k) acc[o] += v[k]*w[k];
        }
    }
    size_t obase = ((size_t)(b*64 + g*16 + og*4)*H1 + oh)*H1 + ow;
    #pragma unroll
    for (int o = 0; o < 4; ++o)
        out[obase + (size_t)o*H1*H1] = fmaxf(acc[o] + fb[og*4 + o], 0.f);
}

extern "C" void kernel_launch(void* const* d_in, const int* in_sizes, int n_in,
                              void* d_out, int out_size, void* d_ws, size_t ws_size,
                              hipStream_t stream)
{
    const float* x1   = (const float*)d_in[0];
    const float* x2   = (const float*)d_in[1];
    const float* mask = (const float*)d_in[2];
    const float* fw0 = (const float*)d_in[3];
    const float* fb0 = (const float*)d_in[4];
    const float* fw1 = (const float*)d_in[5];
    const float* fb1 = (const float*)d_in[6];
    const float* fw2 = (const float*)d_in[7];
    const float* fb2 = (const float*)d_in[8];
    const float* fw3 = (const float*)d_in[9];
    const float* fb3 = (const float*)d_in[10];
    float* out = (float*)d_out;
    char* ws = (char*)d_ws;

    size_t off = 0;
    auto alloc = [&](size_t bytes) { size_t o = off; off += (bytes + 255) & ~(size_t)255; return o; };
    size_t cnt_off = alloc(BATCH*sizeof(int));
    size_t idx_off = alloc((size_t)BATCH*NP*sizeof(int));
    size_t rn_off  = alloc((size_t)BATCH*NP*sizeof(float));
    size_t M_off   = alloc((size_t)BATCH*NP*sizeof(float));
    size_t D_off   = alloc((size_t)BATCH*NP*sizeof(float));
    size_t y_off   = alloc((size_t)BATCH*YPB*sizeof(float));
    size_t remain = (ws_size > off) ? (ws_size - off) : 0;
    int CQ = (int)(remain / ((size_t)BATCH*NP*sizeof(float)));
    if (CQ > NP) CQ = NP;
    if (CQ < 1) CQ = 1;
    size_t S_off = off;
    int NCH = (NP + CQ - 1) / CQ;

    int* cnt   = (int*)(ws + cnt_off);
    int* idx   = (int*)(ws + idx_off);
    float* rnm = (float*)(ws + rn_off);
    float* Mv  = (float*)(ws + M_off);
    float* Dv  = (float*)(ws + D_off);
    float* y   = (float*)(ws + y_off);
    float* S   = (float*)(ws + S_off);

    k1_compact<<<BATCH, 64, 0, stream>>>(mask, cnt, idx);
    k2_norms<<<256, 64, 0, stream>>>(x2, cnt, idx, rnm);
    k_init_stats<<<(BATCH*NP+255)/256, 256, 0, stream>>>(Mv, Dv, cnt);
    for (int ch = 0; ch < NCH; ++ch) {
        k3_scores<<<2048, 64, 0, stream>>>(x2, cnt, idx, rnm, S, ch*CQ, CQ);
        k3b_stats<<<(BATCH*NP+255)/256, 256, 0, stream>>>(S, cnt, Mv, Dv, ch*CQ, CQ);
    }
    for (int ch = 0; ch < NCH; ++ch) {
        if (NCH > 1)
            k3_scores<<<2048, 64, 0, stream>>>(x2, cnt, idx, rnm, S, ch*CQ, CQ);
        k4b_normalize<<<256, 256, 0, stream>>>(S, cnt, Mv, Dv, ch*CQ, CQ);
        k5_paste<<<(BATCH*YPB+255)/256, 256, 0, stream>>>(S, cnt, idx, x1, y, ch*CQ, CQ, ch > 0 ? 1 : 0);
    }
    k6_final<<<dim3(H1, 4, BATCH), 512, 0, stream>>>(y, fw0, fb0, fw1, fb1, fw2, fb2, fw3, fb3, out);
}

// Round 4
// 301.142 us; speedup vs baseline: 1.8308x; 1.3527x over previous
//
#include <hip/hip_runtime.h>
#include <cstdint>

#define BATCH 2
#define CCH 128
#define H2 64
#define NP 4096      /* 64*64 patches */
#define H1 128
#define YPB (CCH*H1*H1) /* 2097152 per batch */

// ---------------- K1: mask patch all-zero test + ordered compaction ----------
__global__ void k1_compact(const float* __restrict__ mask, int* __restrict__ cnt,
                           int* __restrict__ idx)
{
    int b = blockIdx.x;
    int lane = threadIdx.x;
    const float* mb = mask + b * (H2*H2);
    int count = 0;
    for (int it = 0; it < 64; ++it) {
        int p = it * 64 + lane;
        int ph = p >> 6, pw = p & 63;
        float s = 0.f;
        #pragma unroll
        for (int dh = -1; dh <= 1; ++dh) {
            int r = ph + dh;
            if ((unsigned)r < (unsigned)H2) {
                #pragma unroll
                for (int dw = -1; dw <= 1; ++dw) {
                    int c = pw + dw;
                    if ((unsigned)c < (unsigned)H2) s += mb[r*H2 + c];
                }
            }
        }
        bool flag = (s == 0.0f);
        unsigned long long m = __ballot(flag);
        int pre = __popcll(m & ((1ull << lane) - 1ull));
        if (flag) idx[b*NP + count + pre] = p;
        count += __popcll(m);
    }
    if (lane == 0) cnt[b] = count;
}

// ---------------- K2: 1/max(||patch_q||, 1e-4) for selected q ----------------
__global__ void k2_norms(const float* __restrict__ x2, const int* __restrict__ cnt,
                         const int* __restrict__ idx, float* __restrict__ rnorm)
{
    int cnt0 = cnt[0], cnt1 = cnt[1];
    int total = cnt0 + cnt1;
    int lane = threadIdx.x;
    for (int item = blockIdx.x; item < total; item += gridDim.x) {
        int b, j;
        if (item < cnt0) { b = 0; j = item; } else { b = 1; j = item - cnt0; }
        int p = idx[b*NP + j];
        int qh = p >> 6, qw = p & 63;
        const float* xb = x2 + (size_t)b * CCH * H2 * H2;
        float s = 0.f;
        for (int c = lane; c < CCH; c += 64) {
            const float* xc = xb + (size_t)c * H2 * H2;
            #pragma unroll
            for (int dh = -1; dh <= 1; ++dh) {
                int r = qh + dh;
                if ((unsigned)r < (unsigned)H2) {
                    #pragma unroll
                    for (int dw = -1; dw <= 1; ++dw) {
                        int cc = qw + dw;
                        if ((unsigned)cc < (unsigned)H2) { float v = xc[r*H2 + cc]; s += v*v; }
                    }
                }
            }
        }
        #pragma unroll
        for (int off = 32; off > 0; off >>= 1) s += __shfl_down(s, off, 64);
        if (lane == 0) rnorm[b*NP + j] = 1.0f / fmaxf(sqrtf(s), 1e-4f);
    }
}

// ---------------- init online-softmax stats: M=0, D = #masked ----------------
__global__ void k_init_stats(float* __restrict__ M, float* __restrict__ D,
                             const int* __restrict__ cnt)
{
    int t = blockIdx.x * blockDim.x + threadIdx.x;
    if (t >= BATCH*NP) return;
    int b = t >> 12;
    M[t] = 0.f;
    D[t] = (float)(NP - cnt[b]);
}

// ---------------- K3: S[q,s] = <patch_s, patch_q> * rnorm_q -----------------
__global__ void k3_scores(const float* __restrict__ x2, const int* __restrict__ cnt,
                          const int* __restrict__ idx, const float* __restrict__ rnorm,
                          float* __restrict__ S, int base, int CQ)
{
    __shared__ float f[9*CCH];
    int lane = threadIdx.x;
    int cnt0 = cnt[0], cnt1 = cnt[1];
    int nb0 = min(max(cnt0 - base, 0), CQ);
    int nb1 = min(max(cnt1 - base, 0), CQ);
    long total = (long)(nb0 + nb1) * 64;
    for (long item = blockIdx.x; item < total; item += gridDim.x) {
        int b, rem;
        if (item < (long)nb0*64) { b = 0; rem = (int)item; }
        else                     { b = 1; rem = (int)(item - (long)nb0*64); }
        int jq = rem >> 6;
        int h  = rem & 63;
        int jg = base + jq;
        int p = idx[b*NP + jg];
        int qh = p >> 6, qw = p & 63;
        float rn = rnorm[b*NP + jg];
        const float* xb = x2 + (size_t)b * CCH * H2 * H2;
        // stage normalized filter [9][128] in LDS
        for (int t2 = lane; t2 < 9*CCH; t2 += 64) {
            int k = t2 >> 7, c = t2 & 127;
            int dh = k / 3, dw = k % 3;
            int r = qh + dh - 1, cc = qw + dw - 1;
            float v = 0.f;
            if ((unsigned)r < (unsigned)H2 && (unsigned)cc < (unsigned)H2)
                v = xb[((size_t)c*H2 + r)*H2 + cc];
            f[t2] = v * rn;
        }
        __syncthreads();
        float a0=0.f,a1=0.f,a2=0.f,a3=0.f;
        #pragma unroll
        for (int k = 0; k < 9; ++k) {
            int dh = k/3, dw = k%3;
            int rr = h + dh - 1;
            int cc = lane + dw - 1;
            if ((unsigned)rr < (unsigned)H2 && (unsigned)cc < (unsigned)H2) {
                const float* xp = xb + (size_t)rr*H2 + cc;
                const float* fp = f + k*CCH;
                for (int c = 0; c < CCH; c += 4) {
                    a0 += xp[(size_t)(c+0)*H2*H2] * fp[c+0];
                    a1 += xp[(size_t)(c+1)*H2*H2] * fp[c+1];
                    a2 += xp[(size_t)(c+2)*H2*H2] * fp[c+2];
                    a3 += xp[(size_t)(c+3)*H2*H2] * fp[c+3];
                }
            }
        }
        float sv = (a0+a1)+(a2+a3);
        S[((size_t)(b*CQ + jq))*NP + h*64 + lane] = sv;
        __syncthreads();  // protect f before next item's reload
    }
}

// ---------------- K3b: online softmax stats over this chunk ------------------
__global__ void k3b_stats(const float* __restrict__ S, const int* __restrict__ cnt,
                          float* __restrict__ M, float* __restrict__ D, int base, int CQ)
{
    int t = blockIdx.x*blockDim.x + threadIdx.x;
    if (t >= BATCH*NP) return;
    int b = t >> 12, s = t & (NP-1);
    int n = min(max(cnt[b] - base, 0), CQ);
    if (n == 0) return;
    float m = M[t], d = D[t];
    for (int j = 0; j < n; ++j) {
        float l = 10.f * S[((size_t)(b*CQ + j))*NP + s];
        if (l > m) { d = d*__expf(m - l) + 1.f; m = l; }
        else       { d += __expf(l - m); }
    }
    M[t] = m; D[t] = d;
}

// ---------------- K4b: A = exp(10 S - M) / D (in place) ----------------------
__global__ void k4b_normalize(float* __restrict__ S, const int* __restrict__ cnt,
                              const float* __restrict__ M, const float* __restrict__ D,
                              int base, int CQ)
{
    int cnt0 = cnt[0], cnt1 = cnt[1];
    int nb0 = min(max(cnt0 - base, 0), CQ);
    int nb1 = min(max(cnt1 - base, 0), CQ);
    int total = nb0 + nb1;
    for (int item = blockIdx.x; item < total; item += gridDim.x) {
        int b, jq;
        if (item < nb0) { b = 0; jq = item; } else { b = 1; jq = item - nb0; }
        float* row = S + ((size_t)(b*CQ + jq))*NP;
        const float* Mb = M + b*NP;
        const float* Db = D + b*NP;
        for (int s = threadIdx.x; s < NP; s += blockDim.x)
            row[s] = __expf(10.f*row[s] - Mb[s]) / Db[s];
    }
}

// ---------------- K5 v2: paste, LDS-staged A rows + 16-channel accumulator ---
// Identity: with ih_s=((oh+1)>>1)-s, iw_t=((ow+1)>>1)-t (s,t in {0,1}):
//   y[b,co,oh,ow] = 0.25 * sum_j sum_{s,t} A[j,ih_s,iw_t]
//                     * x1[b,co, 2qh_j+2s-(oh&1), 2qw_j+2t-(ow&1)]
// All per-patch overhead (idx decode, A loads, validity) is computed once per
// (b,oh,ow) and amortized over 16 channels; x1 loads coalesced along ow.
#define TJ 32
__global__ void __launch_bounds__(128) k5_paste(const float* __restrict__ A,
    const int* __restrict__ cnt, const int* __restrict__ idx,
    const float* __restrict__ x1, float* __restrict__ y,
    int base, int CQ, int accumulate)
{
    __shared__ float sA[TJ][2][64];
    __shared__ int   sQ[TJ];
    int ow = threadIdx.x;          // 0..127
    int ck = blockIdx.x;           // 0..7 : co chunk of 16
    int oh = blockIdx.y;           // 0..127
    int b  = blockIdx.z;           // 0..1
    int n = min(max(cnt[b] - base, 0), CQ);

    int ohp = oh & 1;
    int ih0 = (oh + 1) >> 1;       // s=0 candidate; s=1 is ih0-1
    int ihv0 = (ih0 <= 63);        // uniform
    int ihv1 = (ih0 >= 1);
    int iw0 = (ow + 1) >> 1;       // per-lane
    int iwv0 = (iw0 <= 63);
    int iwv1 = (iw0 >= 1);

    float acc[16];
    #pragma unroll
    for (int o = 0; o < 16; ++o) acc[o] = 0.f;

    const float* x1c = x1 + ((size_t)(b*CCH + ck*16))*H1*H1;

    for (int j0 = 0; j0 < n; j0 += TJ) {
        int m = min(TJ, n - j0);
        // stage patch positions
        if (ow < m) sQ[ow] = idx[b*NP + base + j0 + ow];
        // stage A rows: lanes 0..63 -> s=0 row, 64..127 -> s=1 row
        for (int u = ow; u < m*128; u += 128) {
            int j  = u >> 7;
            int s  = (u >> 6) & 1;
            int iw = u & 63;
            int ih = ih0 - s;
            int ihc = min(max(ih, 0), 63);
            float v = 0.f;
            if (s == 0 ? ihv0 : ihv1)
                v = A[((size_t)(b*CQ + j0 + j))*NP + ihc*64 + iw];
            sA[j][s][iw] = v;
        }
        __syncthreads();
        for (int j = 0; j < m; ++j) {
            int qp = sQ[j];
            int qh = qp >> 6, qw = qp & 63;
            int rr0 = 2*qh - ohp;          // s=0 (uniform)
            int rr1 = rr0 + 2;             // s=1
            int cc0 = 2*qw - (ow & 1);     // t=0 (per-lane parity)
            int cc1 = cc0 + 2;             // t=1
            int rv0 = ihv0 && ((unsigned)rr0 < (unsigned)H1);
            int rv1 = ihv1 && ((unsigned)rr1 < (unsigned)H1);
            int cv0 = iwv0 && ((unsigned)cc0 < (unsigned)H1);
            int cv1 = iwv1 && ((unsigned)cc1 < (unsigned)H1);
            int iwc0 = min(max(iw0, 0), 63);
            int iwc1 = min(max(iw0 - 1, 0), 63);
            float w00 = (rv0 && cv0) ? sA[j][0][iwc0] : 0.f;
            float w01 = (rv0 && cv1) ? sA[j][0][iwc1] : 0.f;
            float w10 = (rv1 && cv0) ? sA[j][1][iwc0] : 0.f;
            float w11 = (rv1 && cv1) ? sA[j][1][iwc1] : 0.f;
            int r0c = min(max(rr0, 0), H1-1) * H1;
            int r1c = min(max(rr1, 0), H1-1) * H1;
            int c0c = min(max(cc0, 0), H1-1);
            int c1c = min(max(cc1, 0), H1-1);
            int off00 = r0c + c0c;
            int off01 = r0c + c1c;
            int off10 = r1c + c0c;
            int off11 = r1c + c1c;
            #pragma unroll
            for (int co = 0; co < 16; ++co) {
                const float* pc = x1c + (size_t)co*H1*H1;
                acc[co] += w00*pc[off00] + w01*pc[off01]
                         + w10*pc[off10] + w11*pc[off11];
            }
        }
        __syncthreads();
    }
    size_t obase = ((size_t)(b*CCH + ck*16)*H1 + oh)*H1 + ow;
    #pragma unroll
    for (int co = 0; co < 16; ++co) {
        size_t oi = obase + (size_t)co*H1*H1;
        float v = 0.25f*acc[co];
        y[oi] = accumulate ? (y[oi] + v) : v;
    }
}

// ---------------- K6: 4 dilated 3x3 convs + bias + relu, fused ---------------
// 512-thread blocks; each 128-lane group computes 4 of the 16 output channels
// over ALL input channels. og via readfirstlane -> SGPR -> s_load weights.
__global__ void __launch_bounds__(512) k6_final(const float* __restrict__ y,
    const float* __restrict__ fw0, const float* __restrict__ fb0,
    const float* __restrict__ fw1, const float* __restrict__ fb1,
    const float* __restrict__ fw2, const float* __restrict__ fb2,
    const float* __restrict__ fw3, const float* __restrict__ fb3,
    float* __restrict__ out)
{
    int t  = threadIdx.x;
    int ow = t & 127;
    int og = __builtin_amdgcn_readfirstlane(t >> 7);   // 0..3, wave-uniform SGPR
    int oh = blockIdx.x;
    int g  = blockIdx.y;
    int b  = blockIdx.z;
    const float* fw = (g==0)?fw0:(g==1)?fw1:(g==2)?fw2:fw3;
    const float* fb = (g==0)?fb0:(g==1)?fb1:(g==2)?fb2:fb3;
    int r = 1 << g;
    float acc[4];
    #pragma unroll
    for (int o = 0; o < 4; ++o) acc[o] = 0.f;
    const float* yb = y + (size_t)b*YPB;
    const float* fwg = fw + (size_t)og*4*CCH*9;        // uniform base
    for (int c = 0; c < CCH; ++c) {
        const float* yc = yb + (size_t)c*H1*H1;
        float v[9];
        #pragma unroll
        for (int dh = 0; dh < 3; ++dh) {
            int rr = oh + r*(dh-1);
            bool rok = (unsigned)rr < (unsigned)H1;
            #pragma unroll
            for (int dw = 0; dw < 3; ++dw) {
                int cc = ow + r*(dw-1);
                v[dh*3+dw] = (rok && (unsigned)cc < (unsigned)H1) ? yc[rr*H1 + cc] : 0.f;
            }
        }
        #pragma unroll
        for (int o = 0; o < 4; ++o) {
            const float* w = fwg + ((size_t)o*CCH + c)*9;   // uniform -> s_load
            #pragma unroll
            for (int k = 0; k < 9; ++k) acc[o] += v[k]*w[k];
        }
    }
    size_t obase = ((size_t)(b*64 + g*16 + og*4)*H1 + oh)*H1 + ow;
    #pragma unroll
    for (int o = 0; o < 4; ++o)
        out[obase + (size_t)o*H1*H1] = fmaxf(acc[o] + fb[og*4 + o], 0.f);
}

extern "C" void kernel_launch(void* const* d_in, const int* in_sizes, int n_in,
                              void* d_out, int out_size, void* d_ws, size_t ws_size,
                              hipStream_t stream)
{
    const float* x1   = (const float*)d_in[0];
    const float* x2   = (const float*)d_in[1];
    const float* mask = (const float*)d_in[2];
    const float* fw0 = (const float*)d_in[3];
    const float* fb0 = (const float*)d_in[4];
    const float* fw1 = (const float*)d_in[5];
    const float* fb1 = (const float*)d_in[6];
    const float* fw2 = (const float*)d_in[7];
    const float* fb2 = (const float*)d_in[8];
    const float* fw3 = (const float*)d_in[9];
    const float* fb3 = (const float*)d_in[10];
    float* out = (float*)d_out;
    char* ws = (char*)d_ws;

    size_t off = 0;
    auto alloc = [&](size_t bytes) { size_t o = off; off += (bytes + 255) & ~(size_t)255; return o; };
    size_t cnt_off = alloc(BATCH*sizeof(int));
    size_t idx_off = alloc((size_t)BATCH*NP*sizeof(int));
    size_t rn_off  = alloc((size_t)BATCH*NP*sizeof(float));
    size_t M_off   = alloc((size_t)BATCH*NP*sizeof(float));
    size_t D_off   = alloc((size_t)BATCH*NP*sizeof(float));
    size_t y_off   = alloc((size_t)BATCH*YPB*sizeof(float));
    size_t remain = (ws_size > off) ? (ws_size - off) : 0;
    int CQ = (int)(remain / ((size_t)BATCH*NP*sizeof(float)));
    if (CQ > NP) CQ = NP;
    if (CQ < 1) CQ = 1;
    size_t S_off = off;
    int NCH = (NP + CQ - 1) / CQ;

    int* cnt   = (int*)(ws + cnt_off);
    int* idx   = (int*)(ws + idx_off);
    float* rnm = (float*)(ws + rn_off);
    float* Mv  = (float*)(ws + M_off);
    float* Dv  = (float*)(ws + D_off);
    float* y   = (float*)(ws + y_off);
    float* S   = (float*)(ws + S_off);

    k1_compact<<<BATCH, 64, 0, stream>>>(mask, cnt, idx);
    k2_norms<<<256, 64, 0, stream>>>(x2, cnt, idx, rnm);
    k_init_stats<<<(BATCH*NP+255)/256, 256, 0, stream>>>(Mv, Dv, cnt);
    for (int ch = 0; ch < NCH; ++ch) {
        k3_scores<<<2048, 64, 0, stream>>>(x2, cnt, idx, rnm, S, ch*CQ, CQ);
        k3b_stats<<<(BATCH*NP+255)/256, 256, 0, stream>>>(S, cnt, Mv, Dv, ch*CQ, CQ);
    }
    for (int ch = 0; ch < NCH; ++ch) {
        if (NCH > 1)
            k3_scores<<<2048, 64, 0, stream>>>(x2, cnt, idx, rnm, S, ch*CQ, CQ);
        k4b_normalize<<<256, 256, 0, stream>>>(S, cnt, Mv, Dv, ch*CQ, CQ);
        k5_paste<<<dim3(8, H1, BATCH), 128, 0, stream>>>(S, cnt, idx, x1, y, ch*CQ, CQ, ch > 0 ? 1 : 0);
    }
    k6_final<<<dim3(H1, 4, BATCH), 512, 0, stream>>>(y, fw0, fb0, fw1, fb1, fw2, fb2, fw3, fb3, out);
}

// Round 5
// 263.060 us; speedup vs baseline: 2.0959x; 1.1448x over previous
//
#include <hip/hip_runtime.h>
#include <cstdint>

#define BATCH 2
#define CCH 128
#define H2 64
#define NP 4096      /* 64*64 patches */
#define H1 128
#define YPB (CCH*H1*H1) /* 2097152 per batch */

// ---------------- K1: mask patch all-zero test + ordered compaction ----------
__global__ void k1_compact(const float* __restrict__ mask, int* __restrict__ cnt,
                           int* __restrict__ idx)
{
    int b = blockIdx.x;
    int lane = threadIdx.x;
    const float* mb = mask + b * (H2*H2);
    int count = 0;
    for (int it = 0; it < 64; ++it) {
        int p = it * 64 + lane;
        int ph = p >> 6, pw = p & 63;
        float s = 0.f;
        #pragma unroll
        for (int dh = -1; dh <= 1; ++dh) {
            int r = ph + dh;
            if ((unsigned)r < (unsigned)H2) {
                #pragma unroll
                for (int dw = -1; dw <= 1; ++dw) {
                    int c = pw + dw;
                    if ((unsigned)c < (unsigned)H2) s += mb[r*H2 + c];
                }
            }
        }
        bool flag = (s == 0.0f);
        unsigned long long m = __ballot(flag);
        int pre = __popcll(m & ((1ull << lane) - 1ull));
        if (flag) idx[b*NP + count + pre] = p;
        count += __popcll(m);
    }
    if (lane == 0) cnt[b] = count;
}

// ---------------- K2: 1/max(||patch_q||, 1e-4) for selected q ----------------
__global__ void k2_norms(const float* __restrict__ x2, const int* __restrict__ cnt,
                         const int* __restrict__ idx, float* __restrict__ rnorm)
{
    int cnt0 = cnt[0], cnt1 = cnt[1];
    int total = cnt0 + cnt1;
    int lane = threadIdx.x;
    for (int item = blockIdx.x; item < total; item += gridDim.x) {
        int b, j;
        if (item < cnt0) { b = 0; j = item; } else { b = 1; j = item - cnt0; }
        int p = idx[b*NP + j];
        int qh = p >> 6, qw = p & 63;
        const float* xb = x2 + (size_t)b * CCH * H2 * H2;
        float s = 0.f;
        for (int c = lane; c < CCH; c += 64) {
            const float* xc = xb + (size_t)c * H2 * H2;
            #pragma unroll
            for (int dh = -1; dh <= 1; ++dh) {
                int r = qh + dh;
                if ((unsigned)r < (unsigned)H2) {
                    #pragma unroll
                    for (int dw = -1; dw <= 1; ++dw) {
                        int cc = qw + dw;
                        if ((unsigned)cc < (unsigned)H2) { float v = xc[r*H2 + cc]; s += v*v; }
                    }
                }
            }
        }
        #pragma unroll
        for (int off = 32; off > 0; off >>= 1) s += __shfl_down(s, off, 64);
        if (lane == 0) rnorm[b*NP + j] = 1.0f / fmaxf(sqrtf(s), 1e-4f);
    }
}

// ---------------- init online-softmax stats: M=0, D = #masked ----------------
__global__ void k_init_stats(float* __restrict__ M, float* __restrict__ D,
                             const int* __restrict__ cnt)
{
    int t = blockIdx.x * blockDim.x + threadIdx.x;
    if (t >= BATCH*NP) return;
    int b = t >> 12;
    M[t] = 0.f;
    D[t] = (float)(NP - cnt[b]);
}

// ---------------- K3: S[q,s] = <patch_s, patch_q> * rnorm_q -----------------
__global__ void k3_scores(const float* __restrict__ x2, const int* __restrict__ cnt,
                          const int* __restrict__ idx, const float* __restrict__ rnorm,
                          float* __restrict__ S, int base, int CQ)
{
    __shared__ float f[9*CCH];
    int lane = threadIdx.x;
    int cnt0 = cnt[0], cnt1 = cnt[1];
    int nb0 = min(max(cnt0 - base, 0), CQ);
    int nb1 = min(max(cnt1 - base, 0), CQ);
    long total = (long)(nb0 + nb1) * 64;
    for (long item = blockIdx.x; item < total; item += gridDim.x) {
        int b, rem;
        if (item < (long)nb0*64) { b = 0; rem = (int)item; }
        else                     { b = 1; rem = (int)(item - (long)nb0*64); }
        int jq = rem >> 6;
        int h  = rem & 63;
        int jg = base + jq;
        int p = idx[b*NP + jg];
        int qh = p >> 6, qw = p & 63;
        float rn = rnorm[b*NP + jg];
        const float* xb = x2 + (size_t)b * CCH * H2 * H2;
        // stage normalized filter [9][128] in LDS
        for (int t2 = lane; t2 < 9*CCH; t2 += 64) {
            int k = t2 >> 7, c = t2 & 127;
            int dh = k / 3, dw = k % 3;
            int r = qh + dh - 1, cc = qw + dw - 1;
            float v = 0.f;
            if ((unsigned)r < (unsigned)H2 && (unsigned)cc < (unsigned)H2)
                v = xb[((size_t)c*H2 + r)*H2 + cc];
            f[t2] = v * rn;
        }
        __syncthreads();
        float a0=0.f,a1=0.f,a2=0.f,a3=0.f;
        #pragma unroll
        for (int k = 0; k < 9; ++k) {
            int dh = k/3, dw = k%3;
            int rr = h + dh - 1;
            int cc = lane + dw - 1;
            if ((unsigned)rr < (unsigned)H2 && (unsigned)cc < (unsigned)H2) {
                const float* xp = xb + (size_t)rr*H2 + cc;
                const float* fp = f + k*CCH;
                for (int c = 0; c < CCH; c += 4) {
                    a0 += xp[(size_t)(c+0)*H2*H2] * fp[c+0];
                    a1 += xp[(size_t)(c+1)*H2*H2] * fp[c+1];
                    a2 += xp[(size_t)(c+2)*H2*H2] * fp[c+2];
                    a3 += xp[(size_t)(c+3)*H2*H2] * fp[c+3];
                }
            }
        }
        float sv = (a0+a1)+(a2+a3);
        S[((size_t)(b*CQ + jq))*NP + h*64 + lane] = sv;
        __syncthreads();  // protect f before next item's reload
    }
}

// ---------------- K3b: online softmax stats over this chunk ------------------
__global__ void k3b_stats(const float* __restrict__ S, const int* __restrict__ cnt,
                          float* __restrict__ M, float* __restrict__ D, int base, int CQ)
{
    int t = blockIdx.x*blockDim.x + threadIdx.x;
    if (t >= BATCH*NP) return;
    int b = t >> 12, s = t & (NP-1);
    int n = min(max(cnt[b] - base, 0), CQ);
    if (n == 0) return;
    float m = M[t], d = D[t];
    for (int j = 0; j < n; ++j) {
        float l = 10.f * S[((size_t)(b*CQ + j))*NP + s];
        if (l > m) { d = d*__expf(m - l) + 1.f; m = l; }
        else       { d += __expf(l - m); }
    }
    M[t] = m; D[t] = d;
}

// ---------------- K4b: A = exp(10 S - M) / D (in place) ----------------------
__global__ void k4b_normalize(float* __restrict__ S, const int* __restrict__ cnt,
                              const float* __restrict__ M, const float* __restrict__ D,
                              int base, int CQ)
{
    int cnt0 = cnt[0], cnt1 = cnt[1];
    int nb0 = min(max(cnt0 - base, 0), CQ);
    int nb1 = min(max(cnt1 - base, 0), CQ);
    int total = nb0 + nb1;
    for (int item = blockIdx.x; item < total; item += gridDim.x) {
        int b, jq;
        if (item < nb0) { b = 0; jq = item; } else { b = 1; jq = item - nb0; }
        float* row = S + ((size_t)(b*CQ + jq))*NP;
        const float* Mb = M + b*NP;
        const float* Db = D + b*NP;
        for (int s = threadIdx.x; s < NP; s += blockDim.x)
            row[s] = __expf(10.f*row[s] - Mb[s]) / Db[s];
    }
}

// ---------------- K5 v2: paste, LDS-staged A rows + 16-channel accumulator ---
#define TJ 32
__global__ void __launch_bounds__(128) k5_paste(const float* __restrict__ A,
    const int* __restrict__ cnt, const int* __restrict__ idx,
    const float* __restrict__ x1, float* __restrict__ y,
    int base, int CQ, int accumulate)
{
    __shared__ float sA[TJ][2][64];
    __shared__ int   sQ[TJ];
    int ow = threadIdx.x;          // 0..127
    int ck = blockIdx.x;           // 0..7 : co chunk of 16
    int oh = blockIdx.y;           // 0..127
    int b  = blockIdx.z;           // 0..1
    int n = min(max(cnt[b] - base, 0), CQ);

    int ohp = oh & 1;
    int ih0 = (oh + 1) >> 1;       // s=0 candidate; s=1 is ih0-1
    int ihv0 = (ih0 <= 63);        // uniform
    int ihv1 = (ih0 >= 1);
    int iw0 = (ow + 1) >> 1;       // per-lane
    int iwv0 = (iw0 <= 63);
    int iwv1 = (iw0 >= 1);

    float acc[16];
    #pragma unroll
    for (int o = 0; o < 16; ++o) acc[o] = 0.f;

    const float* x1c = x1 + ((size_t)(b*CCH + ck*16))*H1*H1;

    for (int j0 = 0; j0 < n; j0 += TJ) {
        int m = min(TJ, n - j0);
        // stage patch positions
        if (ow < m) sQ[ow] = idx[b*NP + base + j0 + ow];
        // stage A rows: lanes 0..63 -> s=0 row, 64..127 -> s=1 row
        for (int u = ow; u < m*128; u += 128) {
            int j  = u >> 7;
            int s  = (u >> 6) & 1;
            int iw = u & 63;
            int ih = ih0 - s;
            int ihc = min(max(ih, 0), 63);
            float v = 0.f;
            if (s == 0 ? ihv0 : ihv1)
                v = A[((size_t)(b*CQ + j0 + j))*NP + ihc*64 + iw];
            sA[j][s][iw] = v;
        }
        __syncthreads();
        for (int j = 0; j < m; ++j) {
            int qp = sQ[j];
            int qh = qp >> 6, qw = qp & 63;
            int rr0 = 2*qh - ohp;          // s=0 (uniform)
            int rr1 = rr0 + 2;             // s=1
            int cc0 = 2*qw - (ow & 1);     // t=0 (per-lane parity)
            int cc1 = cc0 + 2;             // t=1
            int rv0 = ihv0 && ((unsigned)rr0 < (unsigned)H1);
            int rv1 = ihv1 && ((unsigned)rr1 < (unsigned)H1);
            int cv0 = iwv0 && ((unsigned)cc0 < (unsigned)H1);
            int cv1 = iwv1 && ((unsigned)cc1 < (unsigned)H1);
            int iwc0 = min(max(iw0, 0), 63);
            int iwc1 = min(max(iw0 - 1, 0), 63);
            float w00 = (rv0 && cv0) ? sA[j][0][iwc0] : 0.f;
            float w01 = (rv0 && cv1) ? sA[j][0][iwc1] : 0.f;
            float w10 = (rv1 && cv0) ? sA[j][1][iwc0] : 0.f;
            float w11 = (rv1 && cv1) ? sA[j][1][iwc1] : 0.f;
            int r0c = min(max(rr0, 0), H1-1) * H1;
            int r1c = min(max(rr1, 0), H1-1) * H1;
            int c0c = min(max(cc0, 0), H1-1);
            int c1c = min(max(cc1, 0), H1-1);
            int off00 = r0c + c0c;
            int off01 = r0c + c1c;
            int off10 = r1c + c0c;
            int off11 = r1c + c1c;
            #pragma unroll
            for (int co = 0; co < 16; ++co) {
                const float* pc = x1c + (size_t)co*H1*H1;
                acc[co] += w00*pc[off00] + w01*pc[off01]
                         + w10*pc[off10] + w11*pc[off11];
            }
        }
        __syncthreads();
    }
    size_t obase = ((size_t)(b*CCH + ck*16)*H1 + oh)*H1 + ow;
    #pragma unroll
    for (int co = 0; co < 16; ++co) {
        size_t oi = obase + (size_t)co*H1*H1;
        float v = 0.25f*acc[co];
        y[oi] = accumulate ? (y[oi] + v) : v;
    }
}

// ---------------- K6 v5: 4 dilated 3x3 convs + bias + relu, fused ------------
// 512 threads = 4 groups split over INPUT channels (32 c each, no redundant
// y loads), each group keeps the full 16-channel accumulator (1:16 load:FMA).
// cg via readfirstlane -> SGPR -> weight addresses scalar (s_load). LDS
// cross-group reduce (24 KB). 1024 blocks x 8 waves = 32 waves/CU.
__global__ void __launch_bounds__(512) k6_final(const float* __restrict__ y,
    const float* __restrict__ fw0, const float* __restrict__ fb0,
    const float* __restrict__ fw1, const float* __restrict__ fb1,
    const float* __restrict__ fw2, const float* __restrict__ fb2,
    const float* __restrict__ fw3, const float* __restrict__ fb3,
    float* __restrict__ out)
{
    __shared__ float red[3][16][H1];   // 24 KB
    int t  = threadIdx.x;
    int ow = t & 127;
    int cg = __builtin_amdgcn_readfirstlane(t >> 7);   // 0..3, wave-uniform SGPR
    int oh = blockIdx.x;
    int g  = blockIdx.y;
    int b  = blockIdx.z;
    const float* fw = (g==0)?fw0:(g==1)?fw1:(g==2)?fw2:fw3;
    const float* fb = (g==0)?fb0:(g==1)?fb1:(g==2)?fb2:fb3;
    int r = 1 << g;
    float acc[16];
    #pragma unroll
    for (int o = 0; o < 16; ++o) acc[o] = 0.f;
    const float* yb = y + (size_t)b*YPB + (size_t)cg*32*H1*H1;
    const float* fwc = fw + (size_t)cg*32*9;           // uniform base
    for (int c = 0; c < 32; ++c) {
        const float* yc = yb + (size_t)c*H1*H1;
        float v[9];
        #pragma unroll
        for (int dh = 0; dh < 3; ++dh) {
            int rr = oh + r*(dh-1);
            bool rok = (unsigned)rr < (unsigned)H1;
            #pragma unroll
            for (int dw = 0; dw < 3; ++dw) {
                int cc = ow + r*(dw-1);
                v[dh*3+dw] = (rok && (unsigned)cc < (unsigned)H1) ? yc[rr*H1 + cc] : 0.f;
            }
        }
        #pragma unroll
        for (int o = 0; o < 16; ++o) {
            const float* w = fwc + (size_t)o*CCH*9 + (size_t)c*9;  // uniform -> s_load
            #pragma unroll
            for (int k = 0; k < 9; ++k) acc[o] += v[k]*w[k];
        }
    }
    if (cg > 0) {
        #pragma unroll
        for (int o = 0; o < 16; ++o) red[cg-1][o][ow] = acc[o];
    }
    __syncthreads();
    if (cg == 0) {
        size_t obase = ((size_t)(b*64 + g*16)*H1 + oh)*H1 + ow;
        #pragma unroll
        for (int o = 0; o < 16; ++o) {
            float s = acc[o] + red[0][o][ow] + red[1][o][ow] + red[2][o][ow] + fb[o];
            out[obase + (size_t)o*H1*H1] = fmaxf(s, 0.f);
        }
    }
}

extern "C" void kernel_launch(void* const* d_in, const int* in_sizes, int n_in,
                              void* d_out, int out_size, void* d_ws, size_t ws_size,
                              hipStream_t stream)
{
    const float* x1   = (const float*)d_in[0];
    const float* x2   = (const float*)d_in[1];
    const float* mask = (const float*)d_in[2];
    const float* fw0 = (const float*)d_in[3];
    const float* fb0 = (const float*)d_in[4];
    const float* fw1 = (const float*)d_in[5];
    const float* fb1 = (const float*)d_in[6];
    const float* fw2 = (const float*)d_in[7];
    const float* fb2 = (const float*)d_in[8];
    const float* fw3 = (const float*)d_in[9];
    const float* fb3 = (const float*)d_in[10];
    float* out = (float*)d_out;
    char* ws = (char*)d_ws;

    size_t off = 0;
    auto alloc = [&](size_t bytes) { size_t o = off; off += (bytes + 255) & ~(size_t)255; return o; };
    size_t cnt_off = alloc(BATCH*sizeof(int));
    size_t idx_off = alloc((size_t)BATCH*NP*sizeof(int));
    size_t rn_off  = alloc((size_t)BATCH*NP*sizeof(float));
    size_t M_off   = alloc((size_t)BATCH*NP*sizeof(float));
    size_t D_off   = alloc((size_t)BATCH*NP*sizeof(float));
    size_t y_off   = alloc((size_t)BATCH*YPB*sizeof(float));
    size_t remain = (ws_size > off) ? (ws_size - off) : 0;
    int CQ = (int)(remain / ((size_t)BATCH*NP*sizeof(float)));
    if (CQ > NP) CQ = NP;
    if (CQ < 1) CQ = 1;
    size_t S_off = off;
    int NCH = (NP + CQ - 1) / CQ;

    int* cnt   = (int*)(ws + cnt_off);
    int* idx   = (int*)(ws + idx_off);
    float* rnm = (float*)(ws + rn_off);
    float* Mv  = (float*)(ws + M_off);
    float* Dv  = (float*)(ws + D_off);
    float* y   = (float*)(ws + y_off);
    float* S   = (float*)(ws + S_off);

    k1_compact<<<BATCH, 64, 0, stream>>>(mask, cnt, idx);
    k2_norms<<<256, 64, 0, stream>>>(x2, cnt, idx, rnm);
    k_init_stats<<<(BATCH*NP+255)/256, 256, 0, stream>>>(Mv, Dv, cnt);
    for (int ch = 0; ch < NCH; ++ch) {
        k3_scores<<<2048, 64, 0, stream>>>(x2, cnt, idx, rnm, S, ch*CQ, CQ);
        k3b_stats<<<(BATCH*NP+255)/256, 256, 0, stream>>>(S, cnt, Mv, Dv, ch*CQ, CQ);
    }
    for (int ch = 0; ch < NCH; ++ch) {
        if (NCH > 1)
            k3_scores<<<2048, 64, 0, stream>>>(x2, cnt, idx, rnm, S, ch*CQ, CQ);
        k4b_normalize<<<256, 256, 0, stream>>>(S, cnt, Mv, Dv, ch*CQ, CQ);
        k5_paste<<<dim3(8, H1, BATCH), 128, 0, stream>>>(S, cnt, idx, x1, y, ch*CQ, CQ, ch > 0 ? 1 : 0);
    }
    k6_final<<<dim3(H1, 4, BATCH), 512, 0, stream>>>(y, fw0, fb0, fw1, fb1, fw2, fb2, fw3, fb3, out);
}